// Round 1
// baseline (236.817 us; speedup 1.0000x reference)
//
#include <hip/hip_runtime.h>

// Problem constants
#define BB 2
#define HH 16
#define SS 2048
#define DD 64

constexpr int QTILE = 64;                 // q rows per block (4 waves x 16)
constexpr int KTILE = 64;                 // kv rows per k-tile
constexpr int LDK   = 72;                 // LDS row stride in bf16 elems (pad 64->72, 2-way only)
constexpr int OSIZE = BB * HH * SS * DD;  // 4,194,304

using bf16x8 = __attribute__((ext_vector_type(8))) short;
using f32x4  = __attribute__((ext_vector_type(4))) float;
using u16x8  = __attribute__((ext_vector_type(8))) unsigned short;
using fl4    = __attribute__((ext_vector_type(4))) float;

__device__ __forceinline__ unsigned short f2bf(float f) {
    // round-to-nearest-even fp32 -> bf16 (finite inputs only)
    unsigned int u = __float_as_uint(f);
    return (unsigned short)((u + 0x7fffu + ((u >> 16) & 1u)) >> 16);
}

__device__ __forceinline__ void atomicMaxPosF(float* addr, float v) {
    // valid for non-negative floats: uint ordering == float ordering
    atomicMax(reinterpret_cast<unsigned int*>(addr), __float_as_uint(v));
}

__global__ void init_amax_kernel(float* out) {
    out[OSIZE]     = 0.0f;  // amax_s slot
    out[OSIZE + 1] = 0.0f;  // amax_o slot
}

__global__ __launch_bounds__(256) void fattn_kernel(
    const float* __restrict__ q, const float* __restrict__ k, const float* __restrict__ v,
    const float* __restrict__ dsq, const float* __restrict__ dsk, const float* __restrict__ dsv,
    const float* __restrict__ qss, const float* __restrict__ qso, const float* __restrict__ dss,
    float* __restrict__ out)
{
    const int qt   = blockIdx.x;      // q-tile index 0..31
    const int bh   = blockIdx.y;      // batch*head 0..31
    const int tid  = threadIdx.x;
    const int wave = tid >> 6;        // 0..3
    const int lane = tid & 63;
    const int m16  = lane & 15;       // MFMA row/col-in-16
    const int quad = lane >> 4;       // 0..3

    const float s_scale     = dsq[0] * dsk[0] * 0.125f;   // d_sq*d_sk/sqrt(64)
    const float o_raw_scale = qss[0] * dss[0] * dsv[0];   // applied to P.V
    const float o_q         = qso[0];

    const size_t base = (size_t)bh * SS * DD;
    const int qb = qt * QTILE;

    __shared__ __align__(16) unsigned short Ksh[KTILE * LDK];   // [k_row][d]   bf16
    __shared__ __align__(16) unsigned short Vsh[DD * LDK];      // [d][k_row]   bf16 (transposed)
    __shared__ __align__(16) unsigned short Psh[4][16 * LDK];   // per-wave P scratch

    // ---- Q fragments (A-operand layout: A[m=lane&15][k=quad*8+j]), pre-scaled ----
    bf16x8 qf[2];
    {
        const int qrow = qb + wave * 16 + m16;
        const float* qp = q + base + (size_t)qrow * DD + quad * 8;
        #pragma unroll
        for (int f = 0; f < 2; ++f) {
            #pragma unroll
            for (int j = 0; j < 8; ++j)
                qf[f][j] = (short)f2bf(qp[f * 32 + j] * s_scale);
        }
    }

    f32x4 Oacc[4];
    #pragma unroll
    for (int dt = 0; dt < 4; ++dt)
        #pragma unroll
        for (int r = 0; r < 4; ++r) Oacc[dt][r] = 0.0f;

    float m_i[4], l_i[4];
    #pragma unroll
    for (int r = 0; r < 4; ++r) { m_i[r] = -3.0e38f; l_i[r] = 0.0f; }

    const int nkt = qt + 1;  // causal: only tiles up to the diagonal
    for (int kt = 0; kt < nkt; ++kt) {
        const int kb = kt * KTILE;
        __syncthreads();   // protect LDS from previous iteration's readers

        // ---- stage K (row-major) and V (transposed) into LDS as bf16 ----
        {
            const int r  = tid >> 2;          // kv row 0..63
            const int cb = (tid & 3) * 16;    // col base 0/16/32/48
            const fl4* kp = (const fl4*)(k + base + (size_t)(kb + r) * DD + cb);
            const fl4* vp = (const fl4*)(v + base + (size_t)(kb + r) * DD + cb);
            unsigned short kb16[16];
            #pragma unroll
            for (int c = 0; c < 4; ++c) {
                fl4 kv = kp[c];
                fl4 vv = vp[c];
                #pragma unroll
                for (int j = 0; j < 4; ++j) {
                    kb16[c * 4 + j] = f2bf(kv[j]);
                    Vsh[(cb + c * 4 + j) * LDK + r] = f2bf(vv[j]);
                }
            }
            *(u16x8*)&Ksh[r * LDK + cb]     = *(u16x8*)&kb16[0];
            *(u16x8*)&Ksh[r * LDK + cb + 8] = *(u16x8*)&kb16[8];
        }
        __syncthreads();

        // ---- S = (Q*scale) K^T : four 16x16 n-tiles, K-dim 64 = 2 MFMAs each ----
        f32x4 sacc[4];
        #pragma unroll
        for (int nt = 0; nt < 4; ++nt) {
            f32x4 acc;
            #pragma unroll
            for (int r = 0; r < 4; ++r) acc[r] = 0.0f;
            bf16x8 kf0 = *(bf16x8*)&Ksh[(nt * 16 + m16) * LDK + quad * 8];
            bf16x8 kf1 = *(bf16x8*)&Ksh[(nt * 16 + m16) * LDK + 32 + quad * 8];
            acc = __builtin_amdgcn_mfma_f32_16x16x32_bf16(qf[0], kf0, acc, 0, 0, 0);
            acc = __builtin_amdgcn_mfma_f32_16x16x32_bf16(qf[1], kf1, acc, 0, 0, 0);
            sacc[nt] = acc;
        }

        // ---- causal mask on the diagonal tile (kb == qb there) ----
        if (kt == nkt - 1) {
            #pragma unroll
            for (int nt = 0; nt < 4; ++nt) {
                #pragma unroll
                for (int r = 0; r < 4; ++r) {
                    const int col = nt * 16 + m16;
                    const int row = wave * 16 + quad * 4 + r;
                    if (col > row) sacc[nt][r] = -1.0e30f;
                }
            }
        }

        // ---- online softmax (rows live across the 16 lanes of each quad) ----
        float alpha[4];
        #pragma unroll
        for (int r = 0; r < 4; ++r) {
            float mx = fmaxf(fmaxf(sacc[0][r], sacc[1][r]), fmaxf(sacc[2][r], sacc[3][r]));
            mx = fmaxf(mx, __shfl_xor(mx, 1));
            mx = fmaxf(mx, __shfl_xor(mx, 2));
            mx = fmaxf(mx, __shfl_xor(mx, 4));
            mx = fmaxf(mx, __shfl_xor(mx, 8));
            const float mn = fmaxf(m_i[r], mx);
            alpha[r] = __expf(m_i[r] - mn);
            m_i[r]   = mn;
            float rs = 0.0f;
            #pragma unroll
            for (int nt = 0; nt < 4; ++nt) {
                const float p = __expf(sacc[nt][r] - mn);
                sacc[nt][r] = p;
                rs += p;
            }
            rs += __shfl_xor(rs, 1);
            rs += __shfl_xor(rs, 2);
            rs += __shfl_xor(rs, 4);
            rs += __shfl_xor(rs, 8);
            l_i[r] = l_i[r] * alpha[r] + rs;
        }

        // ---- rescale O accumulator ----
        #pragma unroll
        for (int dt = 0; dt < 4; ++dt)
            #pragma unroll
            for (int r = 0; r < 4; ++r) Oacc[dt][r] *= alpha[r];

        // ---- P: C-layout -> A-layout via per-wave LDS round-trip (m120 pattern) ----
        unsigned short* P = &Psh[wave][0];
        #pragma unroll
        for (int nt = 0; nt < 4; ++nt)
            #pragma unroll
            for (int r = 0; r < 4; ++r)
                P[(quad * 4 + r) * LDK + nt * 16 + m16] = f2bf(sacc[nt][r]);

        bf16x8 pf0 = *(bf16x8*)&P[m16 * LDK + quad * 8];
        bf16x8 pf1 = *(bf16x8*)&P[m16 * LDK + 32 + quad * 8];

        // ---- O += P V  (B-operand from transposed V: contiguous b128 reads) ----
        #pragma unroll
        for (int dt = 0; dt < 4; ++dt) {
            bf16x8 vf0 = *(bf16x8*)&Vsh[(dt * 16 + m16) * LDK + quad * 8];
            bf16x8 vf1 = *(bf16x8*)&Vsh[(dt * 16 + m16) * LDK + 32 + quad * 8];
            Oacc[dt] = __builtin_amdgcn_mfma_f32_16x16x32_bf16(pf0, vf0, Oacc[dt], 0, 0, 0);
            Oacc[dt] = __builtin_amdgcn_mfma_f32_16x16x32_bf16(pf1, vf1, Oacc[dt], 0, 0, 0);
        }
    }

    // ---- epilogue: normalize, scale, store, amax reductions ----
    float amax_o = 0.0f;
    #pragma unroll
    for (int r = 0; r < 4; ++r) {
        const float inv_l = 1.0f / l_i[r];
        const int row = qb + wave * 16 + quad * 4 + r;
        float* op = out + base + (size_t)row * DD + m16;
        #pragma unroll
        for (int dt = 0; dt < 4; ++dt) {
            const float o_raw = Oacc[dt][r] * inv_l * o_raw_scale;
            amax_o = fmaxf(amax_o, fabsf(o_raw));
            op[dt * 16] = o_raw * o_q;
        }
    }
    // max softmax prob in a row = exp(m-m)/l = 1/l
    float amax_s = fmaxf(fmaxf(1.0f / l_i[0], 1.0f / l_i[1]),
                         fmaxf(1.0f / l_i[2], 1.0f / l_i[3]));

    #pragma unroll
    for (int m = 1; m < 64; m <<= 1) {
        amax_o = fmaxf(amax_o, __shfl_xor(amax_o, m));
        amax_s = fmaxf(amax_s, __shfl_xor(amax_s, m));
    }
    if (lane == 0) {
        atomicMaxPosF(out + OSIZE,     amax_s);
        atomicMaxPosF(out + OSIZE + 1, amax_o);
    }
}

extern "C" void kernel_launch(void* const* d_in, const int* in_sizes, int n_in,
                              void* d_out, int out_size, void* d_ws, size_t ws_size,
                              hipStream_t stream) {
    const float* q   = (const float*)d_in[0];
    const float* k   = (const float*)d_in[1];
    const float* v   = (const float*)d_in[2];
    const float* dsq = (const float*)d_in[3];
    const float* dsk = (const float*)d_in[4];
    const float* dsv = (const float*)d_in[5];
    const float* qss = (const float*)d_in[6];
    const float* qso = (const float*)d_in[7];
    const float* dss = (const float*)d_in[8];
    float* out = (float*)d_out;

    init_amax_kernel<<<1, 1, 0, stream>>>(out);

    dim3 grid(SS / QTILE, BB * HH);   // (32, 32)
    fattn_kernel<<<grid, 256, 0, stream>>>(q, k, v, dsq, dsk, dsv, qss, qso, dss, out);
}

// Round 2
// 215.841 us; speedup vs baseline: 1.0972x; 1.0972x over previous
//
#include <hip/hip_runtime.h>

#define BB 2
#define HH 16
#define SS 2048
#define DD 64

constexpr int QTILE = 64;
constexpr int KTILE = 64;
constexpr int LDK   = 72;                 // LDS row stride (bf16 elems) for K / V^T tiles
constexpr int LDP   = 72;                 // LDS row stride for per-wave P scratch
constexpr int OSIZE = BB * HH * SS * DD;  // 4,194,304
constexpr float LOG2E = 1.4426950408889634f;

using bf16x8 = __attribute__((ext_vector_type(8))) short;
using f32x4  = __attribute__((ext_vector_type(4))) float;
using u16x8  = __attribute__((ext_vector_type(8))) unsigned short;
using u16x4  = __attribute__((ext_vector_type(4))) unsigned short;
using fl4    = __attribute__((ext_vector_type(4))) float;

__device__ __forceinline__ unsigned short f2bf(float f) {
    unsigned int u = __float_as_uint(f);
    return (unsigned short)((u + 0x7fffu + ((u >> 16) & 1u)) >> 16);
}

__device__ __forceinline__ void atomicMaxPosF(float* addr, float v) {
    atomicMax(reinterpret_cast<unsigned int*>(addr), __float_as_uint(v));
}

__global__ void init_amax_kernel(float* out) {
    out[OSIZE]     = 0.0f;
    out[OSIZE + 1] = 0.0f;
}

// ---- prepass A: K fp32 -> bf16 (d_scale_k folded), same [bh][s][d] layout ----
__global__ __launch_bounds__(256) void convert_k_kernel(
    const float* __restrict__ k, const float* __restrict__ dsk,
    unsigned short* __restrict__ kbf)
{
    const float sc = dsk[0];
    const int i = (blockIdx.x * 256 + threadIdx.x) * 8;
    fl4 a = *(const fl4*)(k + i);
    fl4 b = *(const fl4*)(k + i + 4);
    u16x8 o;
    #pragma unroll
    for (int j = 0; j < 4; ++j) { o[j] = f2bf(a[j] * sc); o[j + 4] = f2bf(b[j] * sc); }
    *(u16x8*)(kbf + i) = o;
}

// ---- prepass B: V fp32 [bh][s][d] -> bf16 transposed [bh][d][s] (d_scale_v folded) ----
__global__ __launch_bounds__(256) void transpose_v_kernel(
    const float* __restrict__ v, const float* __restrict__ dsv,
    unsigned short* __restrict__ vtb)
{
    __shared__ unsigned short T[64 * 72];
    const float sc = dsv[0];
    const int s0 = blockIdx.x * 64;
    const int bh = blockIdx.y;
    const int t  = threadIdx.x;
    const size_t base = (size_t)bh * SS * DD;

    {
        const int r  = t >> 2;
        const int cb = (t & 3) * 16;
        const fl4* vp = (const fl4*)(v + base + (size_t)(s0 + r) * DD + cb);
        unsigned short tmp[16];
        #pragma unroll
        for (int c = 0; c < 4; ++c) {
            fl4 x = vp[c];
            #pragma unroll
            for (int j = 0; j < 4; ++j) tmp[c * 4 + j] = f2bf(x[j] * sc);
        }
        *(u16x8*)&T[r * 72 + cb]     = *(u16x8*)&tmp[0];
        *(u16x8*)&T[r * 72 + cb + 8] = *(u16x8*)&tmp[8];
    }
    __syncthreads();
    {
        const int dr = t >> 2;
        const int sb = (t & 3) * 16;
        unsigned short tmp[16];
        #pragma unroll
        for (int j = 0; j < 16; ++j) tmp[j] = T[(sb + j) * 72 + dr];
        unsigned short* op = vtb + base + (size_t)dr * SS + s0 + sb;
        *(u16x8*)op       = *(u16x8*)&tmp[0];
        *(u16x8*)(op + 8) = *(u16x8*)&tmp[8];
    }
}

// ---- main flash-attention kernel (S^T orientation) ----
__global__ __launch_bounds__(256) void fattn_kernel(
    const float* __restrict__ q,
    const unsigned short* __restrict__ kbf,     // bf16 K, [bh][s][d], dsk folded
    const unsigned short* __restrict__ vtb,     // bf16 V^T, [bh][d][s], dsv folded
    const float* __restrict__ dsq, const float* __restrict__ qss,
    const float* __restrict__ qso, const float* __restrict__ dss,
    float* __restrict__ out)
{
    const int xr = blockIdx.x;
    const int qt = (xr & 1) ? (31 - (xr >> 1)) : (xr >> 1);   // balanced interleave
    const int bh = blockIdx.y;
    const int tid  = threadIdx.x;
    const int wave = tid >> 6;
    const int lane = tid & 63;
    const int m16  = lane & 15;
    const int quad = lane >> 4;

    const float q_scale = dsq[0] * 0.125f * LOG2E;  // dsq/sqrt(64), log2e folded
    const size_t base = (size_t)bh * SS * DD;
    const int qb = qt * QTILE;

    __shared__ __align__(16) unsigned short Ksh[KTILE * LDK];   // [k_row][d]
    __shared__ __align__(16) unsigned short Vsh[DD * LDK];      // [d][k_row]
    __shared__ __align__(16) unsigned short Psh[4][16 * LDP];   // per-wave [q][k]

    // Q fragment, used as B operand: B[k=d][n=q] == Q[q=m16][d=quad*8+j]
    bf16x8 qf[2];
    {
        const int qrow = qb + wave * 16 + m16;
        const float* qp = q + base + (size_t)qrow * DD + quad * 8;
        #pragma unroll
        for (int f = 0; f < 2; ++f) {
            fl4 a = *(const fl4*)(qp + f * 32);
            fl4 b = *(const fl4*)(qp + f * 32 + 4);
            #pragma unroll
            for (int j = 0; j < 4; ++j) {
                qf[f][j]     = (short)f2bf(a[j] * q_scale);
                qf[f][j + 4] = (short)f2bf(b[j] * q_scale);
            }
        }
    }

    f32x4 Oacc[4];
    #pragma unroll
    for (int dt = 0; dt < 4; ++dt)
        #pragma unroll
        for (int r = 0; r < 4; ++r) Oacc[dt][r] = 0.0f;

    float m_i = -3.0e38f, l_i = 0.0f;   // per-lane: row q = m16 (replicated across quads)

    const int sr  = tid >> 2;           // staging row 0..63
    const int scb = (tid & 3) * 16;     // staging col base

    const int nkt = qt + 1;
    for (int kt = 0; kt < nkt; ++kt) {
        const int kb = kt * KTILE;
        __syncthreads();
        {
            const unsigned short* kg = kbf + base + (size_t)(kb + sr) * DD + scb;
            const unsigned short* vg = vtb + base + (size_t)sr * SS + kb + scb;
            *(u16x8*)&Ksh[sr * LDK + scb]     = *(const u16x8*)kg;
            *(u16x8*)&Ksh[sr * LDK + scb + 8] = *(const u16x8*)(kg + 8);
            *(u16x8*)&Vsh[sr * LDK + scb]     = *(const u16x8*)vg;
            *(u16x8*)&Vsh[sr * LDK + scb + 8] = *(const u16x8*)(vg + 8);
        }
        __syncthreads();

        // S^T = K Q^T : C[row = kc = quad*4+r][col = q = m16]
        f32x4 sacc[4];
        #pragma unroll
        for (int nt = 0; nt < 4; ++nt) {
            f32x4 acc;
            #pragma unroll
            for (int r = 0; r < 4; ++r) acc[r] = 0.0f;
            bf16x8 kf0 = *(bf16x8*)&Ksh[(nt * 16 + m16) * LDK + quad * 8];
            bf16x8 kf1 = *(bf16x8*)&Ksh[(nt * 16 + m16) * LDK + 32 + quad * 8];
            acc = __builtin_amdgcn_mfma_f32_16x16x32_bf16(kf0, qf[0], acc, 0, 0, 0);
            acc = __builtin_amdgcn_mfma_f32_16x16x32_bf16(kf1, qf[1], acc, 0, 0, 0);
            sacc[nt] = acc;
        }

        if (kt == nkt - 1) {   // causal mask on the diagonal tile
            const int qg = qb + wave * 16 + m16;
            #pragma unroll
            for (int nt = 0; nt < 4; ++nt)
                #pragma unroll
                for (int r = 0; r < 4; ++r) {
                    const int kc = kb + nt * 16 + quad * 4 + r;
                    if (kc > qg) sacc[nt][r] = -1.0e30f;
                }
        }

        // online softmax: row q = m16; reduce across quads (xor 16, 32)
        float mx = -3.0e38f;
        #pragma unroll
        for (int nt = 0; nt < 4; ++nt)
            #pragma unroll
            for (int r = 0; r < 4; ++r) mx = fmaxf(mx, sacc[nt][r]);
        mx = fmaxf(mx, __shfl_xor(mx, 16));
        mx = fmaxf(mx, __shfl_xor(mx, 32));
        const float mn = fmaxf(m_i, mx);
        const float alpha = __builtin_amdgcn_exp2f(m_i - mn);
        m_i = mn;

        float rs = 0.0f;
        #pragma unroll
        for (int nt = 0; nt < 4; ++nt)
            #pragma unroll
            for (int r = 0; r < 4; ++r) {
                const float p = __builtin_amdgcn_exp2f(sacc[nt][r] - mn);
                sacc[nt][r] = p;
                rs += p;
            }
        rs += __shfl_xor(rs, 16);
        rs += __shfl_xor(rs, 32);
        l_i = l_i * alpha + rs;

        // rescale O: O rows are q = quad*4+r -> fetch alpha from lane (quad<<4)|(quad*4+r)
        #pragma unroll
        for (int r = 0; r < 4; ++r) {
            const float af = __shfl(alpha, (lane & 48) | (quad * 4 + r));
            #pragma unroll
            for (int dt = 0; dt < 4; ++dt) Oacc[dt][r] *= af;
        }

        // P -> per-wave LDS: lane holds P[q=m16][k = nt*16 + quad*4 + 0..3] (contiguous b64)
        unsigned short* P = &Psh[wave][0];
        #pragma unroll
        for (int nt = 0; nt < 4; ++nt) {
            u16x4 pk;
            #pragma unroll
            for (int r = 0; r < 4; ++r) pk[r] = f2bf(sacc[nt][r]);
            *(u16x4*)&P[m16 * LDP + nt * 16 + quad * 4] = pk;
        }
        bf16x8 pf0 = *(bf16x8*)&P[m16 * LDP + quad * 8];
        bf16x8 pf1 = *(bf16x8*)&P[m16 * LDP + 32 + quad * 8];

        // O += P V : A = P[q][k], B = V^T[k][d]; C[row=q=quad*4+r][col=d=dt*16+m16]
        #pragma unroll
        for (int dt = 0; dt < 4; ++dt) {
            bf16x8 vf0 = *(bf16x8*)&Vsh[(dt * 16 + m16) * LDK + quad * 8];
            bf16x8 vf1 = *(bf16x8*)&Vsh[(dt * 16 + m16) * LDK + 32 + quad * 8];
            Oacc[dt] = __builtin_amdgcn_mfma_f32_16x16x32_bf16(pf0, vf0, Oacc[dt], 0, 0, 0);
            Oacc[dt] = __builtin_amdgcn_mfma_f32_16x16x32_bf16(pf1, vf1, Oacc[dt], 0, 0, 0);
        }
    }

    // epilogue
    const float ss_ = qss[0] * dss[0];
    const float o_q = qso[0];
    float amax_o = 0.0f;
    #pragma unroll
    for (int r = 0; r < 4; ++r) {
        const float lr  = __shfl(l_i, (lane & 48) | (quad * 4 + r));
        const float ivl = ss_ / lr;
        const int row = qb + wave * 16 + quad * 4 + r;
        float* op = out + base + (size_t)row * DD + m16;
        #pragma unroll
        for (int dt = 0; dt < 4; ++dt) {
            const float o_raw = Oacc[dt][r] * ivl;
            amax_o = fmaxf(amax_o, fabsf(o_raw));
            op[dt * 16] = o_raw * o_q;
        }
    }
    float amax_s = 1.0f / l_i;
    #pragma unroll
    for (int m = 1; m < 64; m <<= 1) {
        amax_o = fmaxf(amax_o, __shfl_xor(amax_o, m));
        amax_s = fmaxf(amax_s, __shfl_xor(amax_s, m));
    }
    if (lane == 0) {
        atomicMaxPosF(out + OSIZE,     amax_s);
        atomicMaxPosF(out + OSIZE + 1, amax_o);
    }
}

extern "C" void kernel_launch(void* const* d_in, const int* in_sizes, int n_in,
                              void* d_out, int out_size, void* d_ws, size_t ws_size,
                              hipStream_t stream) {
    const float* q   = (const float*)d_in[0];
    const float* k   = (const float*)d_in[1];
    const float* v   = (const float*)d_in[2];
    const float* dsq = (const float*)d_in[3];
    const float* dsk = (const float*)d_in[4];
    const float* dsv = (const float*)d_in[5];
    const float* qss = (const float*)d_in[6];
    const float* qso = (const float*)d_in[7];
    const float* dss = (const float*)d_in[8];
    float* out = (float*)d_out;

    unsigned short* kbf = (unsigned short*)d_ws;                 // 8 MB
    unsigned short* vtb = (unsigned short*)d_ws + OSIZE;         // 8 MB

    init_amax_kernel<<<1, 1, 0, stream>>>(out);
    convert_k_kernel<<<OSIZE / (256 * 8), 256, 0, stream>>>(k, dsk, kbf);
    transpose_v_kernel<<<dim3(SS / 64, BB * HH), 256, 0, stream>>>(v, dsv, vtb);

    dim3 grid(SS / QTILE, BB * HH);   // (32, 32), qt remapped inside
    fattn_kernel<<<grid, 256, 0, stream>>>(q, kbf, vtb, dsq, qss, qso, dss, out);
}